// Round 5
// baseline (924.675 us; speedup 1.0000x reference)
//
#include <hip/hip_runtime.h>
#include <stdint.h>

#define N_NODES 16384
#define NHN 4096
#define DIM 1024
#define K2D 2048
#define E_TOT 65536
#define E_HH 8192
#define E_OO 40960
// type boundaries: [0,8192) hh, [8192,49152) oo, [49152,65536) ho

typedef __attribute__((ext_vector_type(4))) float f32x4;
typedef __attribute__((ext_vector_type(8))) short s16x8;

static __device__ __forceinline__ unsigned short f2bf(float f) {
  union { float f; unsigned u; } v; v.f = f;
  unsigned r = v.u + 0x7FFF + ((v.u >> 16) & 1);
  return (unsigned short)(r >> 16);
}
static __device__ __forceinline__ float bf2f(unsigned short u) {
  union { unsigned u; float f; } v; v.u = ((unsigned)u) << 16;
  return v.f;
}

// async 16B global -> LDS. LDS side must be wave-uniform base + lane*16;
// global side may be per-lane (gather ok).
static __device__ __forceinline__ void async16(const unsigned short* g, unsigned short* l) {
  __builtin_amdgcn_global_load_lds(
      (const __attribute__((address_space(1))) unsigned int*)g,
      (__attribute__((address_space(3))) unsigned int*)l,
      16, 0, 0);
}

// ---- K0a: cast n_f fp32 -> bf16 into A_node[n][0..1024) (row stride 2048) ----
__global__ __launch_bounds__(256) void k_cast_nf(const float* __restrict__ nf,
                                                 unsigned short* __restrict__ A) {
  int i = blockIdx.x * 256 + threadIdx.x;   // 4194304 float4 groups
  float4 v = ((const float4*)nf)[i];
  int n = i >> 8;
  int k = (i & 255) << 2;
  ushort4 o;
  o.x = f2bf(v.x); o.y = f2bf(v.y); o.z = f2bf(v.z); o.w = f2bf(v.w);
  *(ushort4*)(A + (size_t)n * K2D + k) = o;
}

// ---- K0b: transpose W [2048][1024] fp32 -> Wt [1024][2048] bf16 (5 matrices) ----
__global__ __launch_bounds__(256) void k_transpose(const float* __restrict__ W0,
                                                   const float* __restrict__ W1,
                                                   const float* __restrict__ W2,
                                                   const float* __restrict__ W3,
                                                   const float* __restrict__ W4,
                                                   unsigned short* __restrict__ Wt) {
  int bid = blockIdx.x;
  int w = bid >> 11;
  int tt = bid & 2047;
  int kt = tt & 63, jt = tt >> 6;
  const float* W = (w == 0) ? W0 : (w == 1) ? W1 : (w == 2) ? W2 : (w == 3) ? W3 : W4;
  unsigned short* dst = Wt + (size_t)w * (DIM * K2D);
  __shared__ float s[32][33];
  int c = threadIdx.x & 31, r0 = threadIdx.x >> 5;
#pragma unroll
  for (int i = 0; i < 4; ++i) {
    int r = r0 + i * 8;
    s[r][c] = W[(size_t)(kt * 32 + r) * DIM + jt * 32 + c];
  }
  __syncthreads();
#pragma unroll
  for (int i = 0; i < 4; ++i) {
    int r = r0 + i * 8;
    dst[(size_t)(jt * 32 + r) * K2D + kt * 32 + c] = f2bf(s[c][r]);
  }
}

// ---- K1: fused edge MLP + attention logit. Tile = 64 edges x 512 cols,
// BK=64 (32 K-iterations; halves the vmcnt(0)+barrier drain count vs BK=32).
// grid (2 n-half, 1024 eblk), 256 threads, 4 waves each owning 128 cols.
// LDS 72 KB -> 2 blocks/CU; VGPR+acc ~224 -> 8 waves/CU.
// Swizzle: GLOBAL chunk index cin = c ^ (row&7) within each 128B row; LDS
// stays linear (async16 constraint); fragment reads invert the XOR.
// logit[e] += sum_j relu(feat[e].W[:,j]+b[j]) * Wa[j]
__global__ __launch_bounds__(256) void k_edge_logit(
    const unsigned short* __restrict__ A,      // A_node [N][2048] bf16
    const unsigned short* __restrict__ Wt_all, // 5 x [1024][2048] bf16
    const float* __restrict__ b_hh, const float* __restrict__ b_oo, const float* __restrict__ b_ho,
    const float* __restrict__ Wa,
    const int* __restrict__ esrc, const int* __restrict__ edst,
    float* __restrict__ logit) {
  const int t = threadIdx.x;
  const int half = blockIdx.x;         // 0..1 : 512-col half
  const int e0 = blockIdx.y * 64;
  const unsigned short* Wt;
  const float* bias;
  if (e0 < E_HH)              { Wt = Wt_all;                 bias = b_hh; }
  else if (e0 < E_HH + E_OO)  { Wt = Wt_all + 1 * 2097152;   bias = b_oo; }
  else                        { Wt = Wt_all + 2 * 2097152;   bias = b_ho; }
  const int n0 = half * 512;

  __shared__ __align__(16) unsigned short sA[64 * 64];    //  8 KB
  __shared__ __align__(16) unsigned short sB[512 * 64];   // 64 KB

  // staging coords: 8 chunks (16B) per 64-col row; thread t -> row t>>3,
  // global chunk (t&7) ^ (row&7). row&7 invariant under +32/+64 row steps.
  const int row0 = t >> 3;
  const int cg = ((t & 7) ^ (row0 & 7)) * 8;     // shorts offset in 128B row
  const int s0 = esrc[e0 + row0], s1 = esrc[e0 + row0 + 32];
  const int d0 = edst[e0 + row0], d1 = edst[e0 + row0 + 32];
  const unsigned short* pS0 = A + (size_t)s0 * K2D + cg;
  const unsigned short* pS1 = A + (size_t)s1 * K2D + cg;
  const unsigned short* pD0 = A + (size_t)d0 * K2D + cg;
  const unsigned short* pD1 = A + (size_t)d1 * K2D + cg;
  const unsigned short* pB0 = Wt + (size_t)(n0 + row0) * K2D + cg;
  unsigned short* lA0 = sA + t * 8;            // p=0: rows 0..31
  unsigned short* lA1 = sA + (256 + t) * 8;    // p=1: rows 32..63
  unsigned short* lB0 = sB + t * 8;            // p: rows p*32..p*32+31

  const int lane = t & 63, wid = t >> 6;
  const int quad = lane >> 4, l16 = lane & 15;
  // fragment physical-chunk offsets (shorts) for kk=0,1: invert the XOR
  const int pc0 = ((0 * 4 + quad) ^ (l16 & 7)) * 8;
  const int pc1 = ((1 * 4 + quad) ^ (l16 & 7)) * 8;

  f32x4 acc[4][8];
#pragma unroll
  for (int a = 0; a < 4; ++a)
#pragma unroll
    for (int b = 0; b < 8; ++b) acc[a][b] = (f32x4){0.f, 0.f, 0.f, 0.f};

#pragma unroll 1
  for (int k0 = 0; k0 < K2D; k0 += 64) {
    // k<1024: src rows; k>=1024: dst rows
    const unsigned short* a0 = (k0 < 1024) ? (pS0 + k0) : (pD0 + (k0 - 1024));
    const unsigned short* a1 = (k0 < 1024) ? (pS1 + k0) : (pD1 + (k0 - 1024));
    async16(a0, lA0);
    async16(a1, lA1);
#pragma unroll
    for (int p = 0; p < 16; ++p)
      async16(pB0 + (size_t)p * (32 * K2D) + k0, lB0 + p * 2048);
    __syncthreads();
    s16x8 af[4][2], bfr[8][2];
#pragma unroll
    for (int mt = 0; mt < 4; ++mt) {
      int r8 = (mt * 16 + l16) * 64;
      af[mt][0] = *(const s16x8*)(sA + r8 + pc0);
      af[mt][1] = *(const s16x8*)(sA + r8 + pc1);
    }
#pragma unroll
    for (int nt = 0; nt < 8; ++nt) {
      int r8 = (wid * 128 + nt * 16 + l16) * 64;
      bfr[nt][0] = *(const s16x8*)(sB + r8 + pc0);
      bfr[nt][1] = *(const s16x8*)(sB + r8 + pc1);
    }
#pragma unroll
    for (int kk = 0; kk < 2; ++kk)
#pragma unroll
      for (int mt = 0; mt < 4; ++mt)
#pragma unroll
        for (int nt = 0; nt < 8; ++nt)
          acc[mt][nt] = __builtin_amdgcn_mfma_f32_16x16x32_bf16(af[mt][kk], bfr[nt][kk], acc[mt][nt], 0, 0, 0);
    __syncthreads();
  }

  // epilogue: relu(+bias)*Wa, reduce over this wave's 128 cols, atomic partial
  float rowsum[4][4];
#pragma unroll
  for (int a = 0; a < 4; ++a)
#pragma unroll
    for (int b = 0; b < 4; ++b) rowsum[a][b] = 0.f;
#pragma unroll
  for (int nt = 0; nt < 8; ++nt) {
    int j = n0 + wid * 128 + nt * 16 + l16;
    float bj = bias[j], wj = Wa[j];
#pragma unroll
    for (int mt = 0; mt < 4; ++mt)
#pragma unroll
      for (int r = 0; r < 4; ++r) {
        float v = acc[mt][nt][r] + bj;
        v = v > 0.f ? v : 0.f;
        rowsum[mt][r] += v * wj;
      }
  }
#pragma unroll
  for (int mt = 0; mt < 4; ++mt)
#pragma unroll
    for (int r = 0; r < 4; ++r) {
      float s = rowsum[mt][r];
      s += __shfl_xor(s, 1);
      s += __shfl_xor(s, 2);
      s += __shfl_xor(s, 4);
      s += __shfl_xor(s, 8);
      if (l16 == 0) atomicAdd(&logit[e0 + mt * 16 + quad * 4 + r], s);
    }
}

// ---- K2: CSR build ----
__global__ __launch_bounds__(256) void k_count(const int* __restrict__ edst, int* __restrict__ counts) {
  int e = blockIdx.x * 256 + threadIdx.x;
  atomicAdd(&counts[edst[e]], 1);
}

__global__ __launch_bounds__(1024) void k_scan(const int* __restrict__ counts,
                                               int* __restrict__ offsets,
                                               int* __restrict__ cursor) {
  __shared__ int sT[1024];
  int t = threadIdx.x;
  int base = t * 16;
  int loc[16];
  int s = 0;
#pragma unroll
  for (int i = 0; i < 16; ++i) { loc[i] = s; s += counts[base + i]; }
  sT[t] = s;
  __syncthreads();
  for (int off = 1; off < 1024; off <<= 1) {
    int v = (t >= off) ? sT[t - off] : 0;
    __syncthreads();
    sT[t] += v;
    __syncthreads();
  }
  int excl = sT[t] - s;
#pragma unroll
  for (int i = 0; i < 16; ++i) {
    int o = excl + loc[i];
    offsets[base + i] = o;
    cursor[base + i] = o;
  }
  if (t == 1023) offsets[N_NODES] = sT[1023];
}

__global__ __launch_bounds__(256) void k_fill(const int* __restrict__ edst,
                                              int* __restrict__ cursor,
                                              int* __restrict__ eord) {
  int e = blockIdx.x * 256 + threadIdx.x;
  int p = atomicAdd(&cursor[edst[e]], 1);
  eord[p] = e;
}

// ---- K3: per-node softmax + weighted aggregation -> z half of A_node ----
__global__ __launch_bounds__(256) void k_aggregate(const int* __restrict__ offsets,
                                                   const int* __restrict__ eord,
                                                   const float* __restrict__ logit,
                                                   const int* __restrict__ esrc,
                                                   unsigned short* __restrict__ A) {
  int n = blockIdx.x, t = threadIdx.x;
  int off = offsets[n], end = offsets[n + 1];
  float a0 = 0.f, a1 = 0.f, a2 = 0.f, a3 = 0.f;
  if (end > off) {
    float den = 0.f;
    for (int i = off; i < end; ++i) den += __expf(logit[eord[i]]);
    float rden = 1.0f / den;
    for (int i = off; i < end; ++i) {
      int e = eord[i];
      float al = __expf(logit[e]) * rden;
      int s = esrc[e];
      ushort4 v = *(const ushort4*)(A + (size_t)s * K2D + t * 4);
      a0 += al * bf2f(v.x);
      a1 += al * bf2f(v.y);
      a2 += al * bf2f(v.z);
      a3 += al * bf2f(v.w);
    }
  }
  ushort4 o;
  o.x = f2bf(a0); o.y = f2bf(a1); o.z = f2bf(a2); o.w = f2bf(a3);
  *(ushort4*)(A + (size_t)n * K2D + DIM + t * 4) = o;
}

// ---- K4: node MLP GEMM, tile 64 x 512, BK=64, same structure as K1 ----
// grid (2 n-half, 256 mblk), 256 threads.
__global__ __launch_bounds__(256) void k_node_gemm(
    const unsigned short* __restrict__ A,
    const unsigned short* __restrict__ Wt_hn, const unsigned short* __restrict__ Wt_on,
    const float* __restrict__ b_hn, const float* __restrict__ b_on,
    float* __restrict__ out) {
  const int t = threadIdx.x;
  const int half = blockIdx.x;
  const int m0 = blockIdx.y * 64;
  const unsigned short* Wt = (m0 < NHN) ? Wt_hn : Wt_on;
  const float* bias = (m0 < NHN) ? b_hn : b_on;
  const int n0 = half * 512;

  __shared__ __align__(16) unsigned short sA[64 * 64];
  __shared__ __align__(16) unsigned short sB[512 * 64];

  const int row0 = t >> 3;
  const int cg = ((t & 7) ^ (row0 & 7)) * 8;
  const unsigned short* pA0 = A + (size_t)(m0 + row0) * K2D + cg;
  const unsigned short* pB0 = Wt + (size_t)(n0 + row0) * K2D + cg;
  unsigned short* lA0 = sA + t * 8;
  unsigned short* lA1 = sA + (256 + t) * 8;
  unsigned short* lB0 = sB + t * 8;

  const int lane = t & 63, wid = t >> 6;
  const int quad = lane >> 4, l16 = lane & 15;
  const int pc0 = ((0 * 4 + quad) ^ (l16 & 7)) * 8;
  const int pc1 = ((1 * 4 + quad) ^ (l16 & 7)) * 8;

  f32x4 acc[4][8];
#pragma unroll
  for (int a = 0; a < 4; ++a)
#pragma unroll
    for (int b = 0; b < 8; ++b) acc[a][b] = (f32x4){0.f, 0.f, 0.f, 0.f};

#pragma unroll 1
  for (int k0 = 0; k0 < K2D; k0 += 64) {
    async16(pA0 + k0, lA0);
    async16(pA0 + (size_t)32 * K2D + k0, lA1);
#pragma unroll
    for (int p = 0; p < 16; ++p)
      async16(pB0 + (size_t)p * (32 * K2D) + k0, lB0 + p * 2048);
    __syncthreads();
    s16x8 af[4][2], bfr[8][2];
#pragma unroll
    for (int mt = 0; mt < 4; ++mt) {
      int r8 = (mt * 16 + l16) * 64;
      af[mt][0] = *(const s16x8*)(sA + r8 + pc0);
      af[mt][1] = *(const s16x8*)(sA + r8 + pc1);
    }
#pragma unroll
    for (int nt = 0; nt < 8; ++nt) {
      int r8 = (wid * 128 + nt * 16 + l16) * 64;
      bfr[nt][0] = *(const s16x8*)(sB + r8 + pc0);
      bfr[nt][1] = *(const s16x8*)(sB + r8 + pc1);
    }
#pragma unroll
    for (int kk = 0; kk < 2; ++kk)
#pragma unroll
      for (int mt = 0; mt < 4; ++mt)
#pragma unroll
        for (int nt = 0; nt < 8; ++nt)
          acc[mt][nt] = __builtin_amdgcn_mfma_f32_16x16x32_bf16(af[mt][kk], bfr[nt][kk], acc[mt][nt], 0, 0, 0);
    __syncthreads();
  }
#pragma unroll
  for (int nt = 0; nt < 8; ++nt) {
    int jl = wid * 128 + nt * 16 + l16;
    float bj = bias[n0 + jl];
    int j = n0 + jl;
#pragma unroll
    for (int mt = 0; mt < 4; ++mt)
#pragma unroll
      for (int r = 0; r < 4; ++r) {
        float v = acc[mt][nt][r] + bj;
        v = v > 0.f ? v : 0.f;
        int m = m0 + mt * 16 + quad * 4 + r;
        out[(size_t)m * DIM + j] = v;
      }
  }
}

// ---- workspace layout (bytes) ----
//   A_node : 0          .. 67108864   [16384][2048] bf16
//   Wt     : 67108864   .. 88080384   5 x [1024][2048] bf16 (hh, oo, ho, hn, on)
//   logit  : 88080384   .. 88342528   [65536] f32
//   counts : 88342528   .. 88408064   [16384] i32
//   offsets: 88408064   .. 88473856   [16385] i32 (+pad)
//   cursor : 88473856   .. 88539392   [16384] i32
//   eord   : 88539392   .. 88801536   [65536] i32
extern "C" void kernel_launch(void* const* d_in, const int* in_sizes, int n_in,
                              void* d_out, int out_size, void* d_ws, size_t ws_size,
                              hipStream_t stream) {
  const float* n_f  = (const float*)d_in[0];
  const float* W_hh = (const float*)d_in[1];
  const float* b_hh = (const float*)d_in[2];
  const float* W_oo = (const float*)d_in[3];
  const float* b_oo = (const float*)d_in[4];
  const float* W_ho = (const float*)d_in[5];
  const float* b_ho = (const float*)d_in[6];
  const float* W_a  = (const float*)d_in[7];
  // d_in[8] = b_a : dropped (uniform shift cancels in segment softmax)
  const float* W_hn = (const float*)d_in[9];
  const float* b_hn = (const float*)d_in[10];
  const float* W_on = (const float*)d_in[11];
  const float* b_on = (const float*)d_in[12];
  const int* esrc = (const int*)d_in[13];
  const int* edst = (const int*)d_in[14];
  float* out = (float*)d_out;

  char* ws = (char*)d_ws;
  unsigned short* A_node = (unsigned short*)(ws);
  unsigned short* Wt     = (unsigned short*)(ws + 67108864);
  float* logit  = (float*)(ws + 88080384);
  int* counts   = (int*)(ws + 88342528);
  int* offsets  = (int*)(ws + 88408064);
  int* cursor   = (int*)(ws + 88473856);
  int* eord     = (int*)(ws + 88539392);

  hipMemsetAsync(ws + 88080384, 0, 262144 + 65536, stream);

  k_cast_nf<<<16384, 256, 0, stream>>>(n_f, A_node);
  k_transpose<<<5 * 2048, 256, 0, stream>>>(W_hh, W_oo, W_ho, W_hn, W_on, Wt);
  k_edge_logit<<<dim3(2, E_TOT / 64), 256, 0, stream>>>(A_node, Wt, b_hh, b_oo, b_ho, W_a, esrc, edst, logit);
  k_count<<<E_TOT / 256, 256, 0, stream>>>(edst, counts);
  k_scan<<<1, 1024, 0, stream>>>(counts, offsets, cursor);
  k_fill<<<E_TOT / 256, 256, 0, stream>>>(edst, cursor, eord);
  k_aggregate<<<N_NODES, 256, 0, stream>>>(offsets, eord, logit, esrc, A_node);
  k_node_gemm<<<dim3(2, N_NODES / 64), 256, 0, stream>>>(
      A_node, Wt + 3 * 2097152, Wt + 4 * 2097152, b_hn, b_on, out);
}

// Round 6
// 570.819 us; speedup vs baseline: 1.6199x; 1.6199x over previous
//
#include <hip/hip_runtime.h>
#include <stdint.h>

#define N_NODES 16384
#define NHN 4096
#define DIM 1024
#define K2D 2048
#define E_TOT 65536
#define E_HH 8192
#define E_OO 40960
// type boundaries: [0,8192) hh, [8192,49152) oo, [49152,65536) ho

typedef __attribute__((ext_vector_type(4))) float f32x4;
typedef __attribute__((ext_vector_type(8))) short s16x8;

static __device__ __forceinline__ unsigned short f2bf(float f) {
  union { float f; unsigned u; } v; v.f = f;
  unsigned r = v.u + 0x7FFF + ((v.u >> 16) & 1);
  return (unsigned short)(r >> 16);
}
static __device__ __forceinline__ float bf2f(unsigned short u) {
  union { unsigned u; float f; } v; v.u = ((unsigned)u) << 16;
  return v.f;
}

// async 16B global -> LDS. LDS side must be wave-uniform base + lane*16;
// global side may be per-lane (gather ok).
static __device__ __forceinline__ void async16(const unsigned short* g, unsigned short* l) {
  __builtin_amdgcn_global_load_lds(
      (const __attribute__((address_space(1))) unsigned int*)g,
      (__attribute__((address_space(3))) unsigned int*)l,
      16, 0, 0);
}

// ---- K0a: cast n_f fp32 -> bf16 into A_node[n][0..1024) (row stride 2048) ----
__global__ __launch_bounds__(256) void k_cast_nf(const float* __restrict__ nf,
                                                 unsigned short* __restrict__ A) {
  int i = blockIdx.x * 256 + threadIdx.x;   // 4194304 float4 groups
  float4 v = ((const float4*)nf)[i];
  int n = i >> 8;
  int k = (i & 255) << 2;
  ushort4 o;
  o.x = f2bf(v.x); o.y = f2bf(v.y); o.z = f2bf(v.z); o.w = f2bf(v.w);
  *(ushort4*)(A + (size_t)n * K2D + k) = o;
}

// ---- K0b: transpose W [2048][1024] fp32 -> Wt [1024][2048] bf16 (5 matrices) ----
__global__ __launch_bounds__(256) void k_transpose(const float* __restrict__ W0,
                                                   const float* __restrict__ W1,
                                                   const float* __restrict__ W2,
                                                   const float* __restrict__ W3,
                                                   const float* __restrict__ W4,
                                                   unsigned short* __restrict__ Wt) {
  int bid = blockIdx.x;
  int w = bid >> 11;
  int tt = bid & 2047;
  int kt = tt & 63, jt = tt >> 6;
  const float* W = (w == 0) ? W0 : (w == 1) ? W1 : (w == 2) ? W2 : (w == 3) ? W3 : W4;
  unsigned short* dst = Wt + (size_t)w * (DIM * K2D);
  __shared__ float s[32][33];
  int c = threadIdx.x & 31, r0 = threadIdx.x >> 5;
#pragma unroll
  for (int i = 0; i < 4; ++i) {
    int r = r0 + i * 8;
    s[r][c] = W[(size_t)(kt * 32 + r) * DIM + jt * 32 + c];
  }
  __syncthreads();
#pragma unroll
  for (int i = 0; i < 4; ++i) {
    int r = r0 + i * 8;
    dst[(size_t)(jt * 32 + r) * K2D + kt * 32 + c] = f2bf(s[c][r]);
  }
}

// ---- K1: fused edge MLP + attention logit. Tile = 64 edges x 512 cols,
// BK=64 (32 K-iterations). grid (2 n-half, 1024 eblk), 256 threads.
// Register discipline (round-5 lesson): fragments loaded PER kk-half
// (#pragma unroll 1) -> ~48 live frag VGPRs instead of 96; with 128 acc
// regs total ~230 <= 256 -> 2 waves/SIMD (2 blocks/CU). Pinned via
// __launch_bounds__(256,2).
// Swizzle (round-5, measured 0 conflicts): global chunk (t&7)^(row&7) within
// each 128B row; LDS linear (async16 constraint); reads invert the XOR.
// logit[e] += sum_j relu(feat[e].W[:,j]+b[j]) * Wa[j]
__global__ __launch_bounds__(256, 2) void k_edge_logit(
    const unsigned short* __restrict__ A,      // A_node [N][2048] bf16
    const unsigned short* __restrict__ Wt_all, // 5 x [1024][2048] bf16
    const float* __restrict__ b_hh, const float* __restrict__ b_oo, const float* __restrict__ b_ho,
    const float* __restrict__ Wa,
    const int* __restrict__ esrc, const int* __restrict__ edst,
    float* __restrict__ logit) {
  const int t = threadIdx.x;
  const int half = blockIdx.x;         // 0..1 : 512-col half
  const int e0 = blockIdx.y * 64;
  const unsigned short* Wt;
  const float* bias;
  if (e0 < E_HH)              { Wt = Wt_all;                 bias = b_hh; }
  else if (e0 < E_HH + E_OO)  { Wt = Wt_all + 1 * 2097152;   bias = b_oo; }
  else                        { Wt = Wt_all + 2 * 2097152;   bias = b_ho; }
  const int n0 = half * 512;

  __shared__ __align__(16) unsigned short sA[64 * 64];    //  8 KB
  __shared__ __align__(16) unsigned short sB[512 * 64];   // 64 KB

  const int row0 = t >> 3;
  const int cg = ((t & 7) ^ (row0 & 7)) * 8;     // swizzled global chunk (shorts)
  const int s0 = esrc[e0 + row0], s1 = esrc[e0 + row0 + 32];
  const int d0 = edst[e0 + row0], d1 = edst[e0 + row0 + 32];
  const unsigned short* pS0 = A + (size_t)s0 * K2D + cg;
  const unsigned short* pS1 = A + (size_t)s1 * K2D + cg;
  const unsigned short* pD0 = A + (size_t)d0 * K2D + cg;
  const unsigned short* pD1 = A + (size_t)d1 * K2D + cg;
  const unsigned short* pB0 = Wt + (size_t)(n0 + row0) * K2D + cg;
  unsigned short* lA0 = sA + t * 8;            // p=0: rows 0..31
  unsigned short* lA1 = sA + (256 + t) * 8;    // p=1: rows 32..63
  unsigned short* lB0 = sB + t * 8;            // p: rows p*32..p*32+31

  const int lane = t & 63, wid = t >> 6;
  const int quad = lane >> 4, l16 = lane & 15;

  f32x4 acc[4][8];
#pragma unroll
  for (int a = 0; a < 4; ++a)
#pragma unroll
    for (int b = 0; b < 8; ++b) acc[a][b] = (f32x4){0.f, 0.f, 0.f, 0.f};

#pragma unroll 1
  for (int k0 = 0; k0 < K2D; k0 += 64) {
    // k<1024: src rows; k>=1024: dst rows
    const unsigned short* a0 = (k0 < 1024) ? (pS0 + k0) : (pD0 + (k0 - 1024));
    const unsigned short* a1 = (k0 < 1024) ? (pS1 + k0) : (pD1 + (k0 - 1024));
    async16(a0, lA0);
    async16(a1, lA1);
#pragma unroll
    for (int p = 0; p < 16; ++p)
      async16(pB0 + (size_t)p * (32 * K2D) + k0, lB0 + p * 2048);
    __syncthreads();
#pragma unroll 1
    for (int kk = 0; kk < 2; ++kk) {
      const int pc = ((kk * 4 + quad) ^ (l16 & 7)) * 8;  // de-swizzled chunk
      s16x8 af[4], bfr[8];
#pragma unroll
      for (int mt = 0; mt < 4; ++mt)
        af[mt] = *(const s16x8*)(sA + (mt * 16 + l16) * 64 + pc);
#pragma unroll
      for (int nt = 0; nt < 8; ++nt)
        bfr[nt] = *(const s16x8*)(sB + (wid * 128 + nt * 16 + l16) * 64 + pc);
#pragma unroll
      for (int mt = 0; mt < 4; ++mt)
#pragma unroll
        for (int nt = 0; nt < 8; ++nt)
          acc[mt][nt] = __builtin_amdgcn_mfma_f32_16x16x32_bf16(af[mt], bfr[nt], acc[mt][nt], 0, 0, 0);
    }
    __syncthreads();
  }

  // epilogue: relu(+bias)*Wa, reduce over this wave's 128 cols, atomic partial
  float rowsum[4][4];
#pragma unroll
  for (int a = 0; a < 4; ++a)
#pragma unroll
    for (int b = 0; b < 4; ++b) rowsum[a][b] = 0.f;
#pragma unroll
  for (int nt = 0; nt < 8; ++nt) {
    int j = n0 + wid * 128 + nt * 16 + l16;
    float bj = bias[j], wj = Wa[j];
#pragma unroll
    for (int mt = 0; mt < 4; ++mt)
#pragma unroll
      for (int r = 0; r < 4; ++r) {
        float v = acc[mt][nt][r] + bj;
        v = v > 0.f ? v : 0.f;
        rowsum[mt][r] += v * wj;
      }
  }
#pragma unroll
  for (int mt = 0; mt < 4; ++mt)
#pragma unroll
    for (int r = 0; r < 4; ++r) {
      float s = rowsum[mt][r];
      s += __shfl_xor(s, 1);
      s += __shfl_xor(s, 2);
      s += __shfl_xor(s, 4);
      s += __shfl_xor(s, 8);
      if (l16 == 0) atomicAdd(&logit[e0 + mt * 16 + quad * 4 + r], s);
    }
}

// ---- K2: CSR build ----
__global__ __launch_bounds__(256) void k_count(const int* __restrict__ edst, int* __restrict__ counts) {
  int e = blockIdx.x * 256 + threadIdx.x;
  atomicAdd(&counts[edst[e]], 1);
}

__global__ __launch_bounds__(1024) void k_scan(const int* __restrict__ counts,
                                               int* __restrict__ offsets,
                                               int* __restrict__ cursor) {
  __shared__ int sT[1024];
  int t = threadIdx.x;
  int base = t * 16;
  int loc[16];
  int s = 0;
#pragma unroll
  for (int i = 0; i < 16; ++i) { loc[i] = s; s += counts[base + i]; }
  sT[t] = s;
  __syncthreads();
  for (int off = 1; off < 1024; off <<= 1) {
    int v = (t >= off) ? sT[t - off] : 0;
    __syncthreads();
    sT[t] += v;
    __syncthreads();
  }
  int excl = sT[t] - s;
#pragma unroll
  for (int i = 0; i < 16; ++i) {
    int o = excl + loc[i];
    offsets[base + i] = o;
    cursor[base + i] = o;
  }
  if (t == 1023) offsets[N_NODES] = sT[1023];
}

__global__ __launch_bounds__(256) void k_fill(const int* __restrict__ edst,
                                              int* __restrict__ cursor,
                                              int* __restrict__ eord) {
  int e = blockIdx.x * 256 + threadIdx.x;
  int p = atomicAdd(&cursor[edst[e]], 1);
  eord[p] = e;
}

// ---- K3: per-node softmax + weighted aggregation -> z half of A_node ----
__global__ __launch_bounds__(256) void k_aggregate(const int* __restrict__ offsets,
                                                   const int* __restrict__ eord,
                                                   const float* __restrict__ logit,
                                                   const int* __restrict__ esrc,
                                                   unsigned short* __restrict__ A) {
  int n = blockIdx.x, t = threadIdx.x;
  int off = offsets[n], end = offsets[n + 1];
  float a0 = 0.f, a1 = 0.f, a2 = 0.f, a3 = 0.f;
  if (end > off) {
    float den = 0.f;
    for (int i = off; i < end; ++i) den += __expf(logit[eord[i]]);
    float rden = 1.0f / den;
    for (int i = off; i < end; ++i) {
      int e = eord[i];
      float al = __expf(logit[e]) * rden;
      int s = esrc[e];
      ushort4 v = *(const ushort4*)(A + (size_t)s * K2D + t * 4);
      a0 += al * bf2f(v.x);
      a1 += al * bf2f(v.y);
      a2 += al * bf2f(v.z);
      a3 += al * bf2f(v.w);
    }
  }
  ushort4 o;
  o.x = f2bf(a0); o.y = f2bf(a1); o.z = f2bf(a2); o.w = f2bf(a3);
  *(ushort4*)(A + (size_t)n * K2D + DIM + t * 4) = o;
}

// ---- K4: node MLP GEMM, tile 64 x 512, BK=64, same structure as K1 ----
// grid (2 n-half, 256 mblk), 256 threads.
__global__ __launch_bounds__(256, 2) void k_node_gemm(
    const unsigned short* __restrict__ A,
    const unsigned short* __restrict__ Wt_hn, const unsigned short* __restrict__ Wt_on,
    const float* __restrict__ b_hn, const float* __restrict__ b_on,
    float* __restrict__ out) {
  const int t = threadIdx.x;
  const int half = blockIdx.x;
  const int m0 = blockIdx.y * 64;
  const unsigned short* Wt = (m0 < NHN) ? Wt_hn : Wt_on;
  const float* bias = (m0 < NHN) ? b_hn : b_on;
  const int n0 = half * 512;

  __shared__ __align__(16) unsigned short sA[64 * 64];
  __shared__ __align__(16) unsigned short sB[512 * 64];

  const int row0 = t >> 3;
  const int cg = ((t & 7) ^ (row0 & 7)) * 8;
  const unsigned short* pA0 = A + (size_t)(m0 + row0) * K2D + cg;
  const unsigned short* pB0 = Wt + (size_t)(n0 + row0) * K2D + cg;
  unsigned short* lA0 = sA + t * 8;
  unsigned short* lA1 = sA + (256 + t) * 8;
  unsigned short* lB0 = sB + t * 8;

  const int lane = t & 63, wid = t >> 6;
  const int quad = lane >> 4, l16 = lane & 15;

  f32x4 acc[4][8];
#pragma unroll
  for (int a = 0; a < 4; ++a)
#pragma unroll
    for (int b = 0; b < 8; ++b) acc[a][b] = (f32x4){0.f, 0.f, 0.f, 0.f};

#pragma unroll 1
  for (int k0 = 0; k0 < K2D; k0 += 64) {
    async16(pA0 + k0, lA0);
    async16(pA0 + (size_t)32 * K2D + k0, lA1);
#pragma unroll
    for (int p = 0; p < 16; ++p)
      async16(pB0 + (size_t)p * (32 * K2D) + k0, lB0 + p * 2048);
    __syncthreads();
#pragma unroll 1
    for (int kk = 0; kk < 2; ++kk) {
      const int pc = ((kk * 4 + quad) ^ (l16 & 7)) * 8;
      s16x8 af[4], bfr[8];
#pragma unroll
      for (int mt = 0; mt < 4; ++mt)
        af[mt] = *(const s16x8*)(sA + (mt * 16 + l16) * 64 + pc);
#pragma unroll
      for (int nt = 0; nt < 8; ++nt)
        bfr[nt] = *(const s16x8*)(sB + (wid * 128 + nt * 16 + l16) * 64 + pc);
#pragma unroll
      for (int mt = 0; mt < 4; ++mt)
#pragma unroll
        for (int nt = 0; nt < 8; ++nt)
          acc[mt][nt] = __builtin_amdgcn_mfma_f32_16x16x32_bf16(af[mt], bfr[nt], acc[mt][nt], 0, 0, 0);
    }
    __syncthreads();
  }
#pragma unroll
  for (int nt = 0; nt < 8; ++nt) {
    int jl = wid * 128 + nt * 16 + l16;
    float bj = bias[n0 + jl];
    int j = n0 + jl;
#pragma unroll
    for (int mt = 0; mt < 4; ++mt)
#pragma unroll
      for (int r = 0; r < 4; ++r) {
        float v = acc[mt][nt][r] + bj;
        v = v > 0.f ? v : 0.f;
        int m = m0 + mt * 16 + quad * 4 + r;
        out[(size_t)m * DIM + j] = v;
      }
  }
}

// ---- workspace layout (bytes) ----
//   A_node : 0          .. 67108864   [16384][2048] bf16
//   Wt     : 67108864   .. 88080384   5 x [1024][2048] bf16 (hh, oo, ho, hn, on)
//   logit  : 88080384   .. 88342528   [65536] f32
//   counts : 88342528   .. 88408064   [16384] i32
//   offsets: 88408064   .. 88473856   [16385] i32 (+pad)
//   cursor : 88473856   .. 88539392   [16384] i32
//   eord   : 88539392   .. 88801536   [65536] i32
extern "C" void kernel_launch(void* const* d_in, const int* in_sizes, int n_in,
                              void* d_out, int out_size, void* d_ws, size_t ws_size,
                              hipStream_t stream) {
  const float* n_f  = (const float*)d_in[0];
  const float* W_hh = (const float*)d_in[1];
  const float* b_hh = (const float*)d_in[2];
  const float* W_oo = (const float*)d_in[3];
  const float* b_oo = (const float*)d_in[4];
  const float* W_ho = (const float*)d_in[5];
  const float* b_ho = (const float*)d_in[6];
  const float* W_a  = (const float*)d_in[7];
  // d_in[8] = b_a : dropped (uniform shift cancels in segment softmax)
  const float* W_hn = (const float*)d_in[9];
  const float* b_hn = (const float*)d_in[10];
  const float* W_on = (const float*)d_in[11];
  const float* b_on = (const float*)d_in[12];
  const int* esrc = (const int*)d_in[13];
  const int* edst = (const int*)d_in[14];
  float* out = (float*)d_out;

  char* ws = (char*)d_ws;
  unsigned short* A_node = (unsigned short*)(ws);
  unsigned short* Wt     = (unsigned short*)(ws + 67108864);
  float* logit  = (float*)(ws + 88080384);
  int* counts   = (int*)(ws + 88342528);
  int* offsets  = (int*)(ws + 88408064);
  int* cursor   = (int*)(ws + 88473856);
  int* eord     = (int*)(ws + 88539392);

  hipMemsetAsync(ws + 88080384, 0, 262144 + 65536, stream);

  k_cast_nf<<<16384, 256, 0, stream>>>(n_f, A_node);
  k_transpose<<<5 * 2048, 256, 0, stream>>>(W_hh, W_oo, W_ho, W_hn, W_on, Wt);
  k_edge_logit<<<dim3(2, E_TOT / 64), 256, 0, stream>>>(A_node, Wt, b_hh, b_oo, b_ho, W_a, esrc, edst, logit);
  k_count<<<E_TOT / 256, 256, 0, stream>>>(edst, counts);
  k_scan<<<1, 1024, 0, stream>>>(counts, offsets, cursor);
  k_fill<<<E_TOT / 256, 256, 0, stream>>>(edst, cursor, eord);
  k_aggregate<<<N_NODES, 256, 0, stream>>>(offsets, eord, logit, esrc, A_node);
  k_node_gemm<<<dim3(2, N_NODES / 64), 256, 0, stream>>>(
      A_node, Wt + 3 * 2097152, Wt + 4 * 2097152, b_hn, b_on, out);
}